// Round 15
// baseline (320.510 us; speedup 1.0000x reference)
//
#include <hip/hip_runtime.h>
#include <math.h>

#define NNODES 100000
#define NEDGES 1600000
#define HF 64
#define NBUCK_SHIFT 9
#define NBUCK 256                                // counter slots (power of 2)
#define NBUCK_USED ((NNODES + 511) >> 9)         // 196 buckets actually used
#define BCAP 9216                                // per-bucket capacity (mean 8192 + 11 sigma)
#define KB_BLOCKS 1024

// ======================= CSR build (fixed-capacity buckets) ===============
__global__ __launch_bounds__(256) void k_ginit(int* __restrict__ gcur)
{
    gcur[threadIdx.x] = threadIdx.x * BCAP;
}

// pass 1: partition edges into dst-buckets; payload packed (src<<9)|localdst
__global__ __launch_bounds__(256) void k_bucket(
    const int* __restrict__ src, const int* __restrict__ dst,
    int* __restrict__ gcur, int* __restrict__ epack, int E)
{
    __shared__ int hist[NBUCK];
    const int tid = threadIdx.x;
    const int EPB = (E + KB_BLOCKS - 1) / KB_BLOCKS;
    const int e0 = blockIdx.x * EPB;
    const int e1 = min(E, e0 + EPB);

    hist[tid] = 0;
    __syncthreads();
    for (int i = e0 + tid; i < e1; i += 256)
        atomicAdd(&hist[dst[i] >> NBUCK_SHIFT], 1);
    __syncthreads();
    int cnt = hist[tid];
    int base = (cnt > 0) ? atomicAdd(&gcur[tid], cnt) : 0;
    __syncthreads();
    hist[tid] = base;
    __syncthreads();
    for (int i = e0 + tid; i < e1; i += 256) {
        int d = dst[i];
        int r = atomicAdd(&hist[d >> NBUCK_SHIFT], 1);
        epack[r] = (src[i] << NBUCK_SHIFT) | (d & 511);
    }
}

// pass 2: per-bucket local CSR — LDS histogram + scan + scatter.
__global__ __launch_bounds__(256) void k_local(
    const int* __restrict__ epack, const int* __restrict__ gcur,
    int* __restrict__ curdeg, int* __restrict__ esrc)
{
    __shared__ int lhist[512];
    __shared__ int lcur[512];
    __shared__ int s[256];
    const int b = blockIdx.x;
    const int tid = threadIdx.x;
    const int e0 = b * BCAP;
    const int e1 = gcur[b];
    const int n0 = b << NBUCK_SHIFT;

    lhist[tid] = 0;
    lhist[tid + 256] = 0;
    __syncthreads();
    for (int i = e0 + tid; i < e1; i += 256)
        atomicAdd(&lhist[epack[i] & 511], 1);
    __syncthreads();

    int v0 = lhist[2 * tid], v1 = lhist[2 * tid + 1];
    int tsum = v0 + v1;
    s[tid] = tsum;
    __syncthreads();
    for (int off = 1; off < 256; off <<= 1) {
        int t = (tid >= off) ? s[tid - off] : 0;
        __syncthreads();
        s[tid] += t;
        __syncthreads();
    }
    int run = s[tid] - tsum;
    lcur[2 * tid] = run;
    lcur[2 * tid + 1] = run + v0;
    int node0 = n0 + 2 * tid;
    if (node0 < NNODES)     curdeg[node0]     = ((e0 + run + v0) << 9) | v0;
    if (node0 + 1 < NNODES) curdeg[node0 + 1] = ((e0 + run + v0 + v1) << 9) | v1;
    __syncthreads();

    for (int i = e0 + tid; i < e1; i += 256) {
        int p = epack[i];
        int pos = atomicAdd(&lcur[p & 511], 1);
        esrc[e0 + pos] = ((unsigned)p) >> NBUCK_SHIFT;
    }
}

// ======================= tiled GEMM: 128x64, 8x4/thread, KS=32 ============
// R13-proven base + register prefetch: chunk c+1 global loads issued BEFORE
// chunk c's FMA (latency hidden under ~2048 FMAs); single 25.6KB LDS buffer.
template <int K>
__global__ __launch_bounds__(256) void gemm_tile(
    const float* __restrict__ x, const float* __restrict__ W,
    const float* __restrict__ al, const float* __restrict__ ar,
    float* __restrict__ feat, float* __restrict__ el, float* __restrict__ er,
    int n)
{
    constexpr int KS = 32;
    constexpr int NC = K / KS;
    __shared__ float xs[KS][132];
    __shared__ float wt[KS][68];

    const int tid = threadIdx.x;
    const int tx = tid & 15;
    const int ty = tid >> 4;
    const int row0 = blockIdx.x * 128;

    float acc[8][4];
#pragma unroll
    for (int i = 0; i < 8; ++i)
#pragma unroll
        for (int j = 0; j < 4; ++j) acc[i][j] = 0.f;

    float4 xr[4], wr[2];
    // ---- load + store chunk 0 ----
#pragma unroll
    for (int jj = 0; jj < 4; ++jj) {
        int j = tid + jj * 256;
        int gr = row0 + (j >> 3);
        xr[jj] = make_float4(0.f, 0.f, 0.f, 0.f);
        if (gr < n) xr[jj] = *(const float4*)(x + (size_t)gr * K + 4 * (j & 7));
    }
#pragma unroll
    for (int jj = 0; jj < 2; ++jj) {
        int j = tid + jj * 256;
        wr[jj] = *(const float4*)(W + (size_t)(j >> 3) * K + 4 * (j & 7));
    }
#pragma unroll
    for (int jj = 0; jj < 4; ++jj) {
        int j = tid + jj * 256;
        int r = j >> 3, k4 = j & 7;
        xs[4 * k4 + 0][r] = xr[jj].x;
        xs[4 * k4 + 1][r] = xr[jj].y;
        xs[4 * k4 + 2][r] = xr[jj].z;
        xs[4 * k4 + 3][r] = xr[jj].w;
    }
#pragma unroll
    for (int jj = 0; jj < 2; ++jj) {
        int j = tid + jj * 256;
        int c = j >> 3, k4 = j & 7;
        wt[4 * k4 + 0][c] = wr[jj].x;
        wt[4 * k4 + 1][c] = wr[jj].y;
        wt[4 * k4 + 2][c] = wr[jj].z;
        wt[4 * k4 + 3][c] = wr[jj].w;
    }
    __syncthreads();

#pragma unroll
    for (int c = 0; c < NC; ++c) {
        // prefetch next chunk into regs (in flight during FMA below)
        if (c + 1 < NC) {
            const int ks = (c + 1) * KS;
#pragma unroll
            for (int jj = 0; jj < 4; ++jj) {
                int j = tid + jj * 256;
                int gr = row0 + (j >> 3);
                xr[jj] = make_float4(0.f, 0.f, 0.f, 0.f);
                if (gr < n) xr[jj] = *(const float4*)(x + (size_t)gr * K + ks + 4 * (j & 7));
            }
#pragma unroll
            for (int jj = 0; jj < 2; ++jj) {
                int j = tid + jj * 256;
                wr[jj] = *(const float4*)(W + (size_t)(j >> 3) * K + ks + 4 * (j & 7));
            }
        }
        // FMA on current chunk
#pragma unroll 8
        for (int k = 0; k < KS; ++k) {
            float4 a0 = *(const float4*)&xs[k][8 * ty + 0];
            float4 a1 = *(const float4*)&xs[k][8 * ty + 4];
            float4 b  = *(const float4*)&wt[k][4 * tx];
            float av[8] = {a0.x, a0.y, a0.z, a0.w, a1.x, a1.y, a1.z, a1.w};
            float bv[4] = {b.x, b.y, b.z, b.w};
#pragma unroll
            for (int i = 0; i < 8; ++i)
#pragma unroll
                for (int j = 0; j < 4; ++j)
                    acc[i][j] += av[i] * bv[j];
        }
        // store prefetched regs into LDS for next iteration
        if (c + 1 < NC) {
            __syncthreads();
#pragma unroll
            for (int jj = 0; jj < 4; ++jj) {
                int j = tid + jj * 256;
                int r = j >> 3, k4 = j & 7;
                xs[4 * k4 + 0][r] = xr[jj].x;
                xs[4 * k4 + 1][r] = xr[jj].y;
                xs[4 * k4 + 2][r] = xr[jj].z;
                xs[4 * k4 + 3][r] = xr[jj].w;
            }
#pragma unroll
            for (int jj = 0; jj < 2; ++jj) {
                int j = tid + jj * 256;
                int cc = j >> 3, k4 = j & 7;
                wt[4 * k4 + 0][cc] = wr[jj].x;
                wt[4 * k4 + 1][cc] = wr[jj].y;
                wt[4 * k4 + 2][cc] = wr[jj].z;
                wt[4 * k4 + 3][cc] = wr[jj].w;
            }
            __syncthreads();
        }
    }

    const float4 ald = *(const float4*)(al + 4 * tx);
    const float4 ard = *(const float4*)(ar + 4 * tx);
#pragma unroll
    for (int i = 0; i < 8; ++i) {
        int row = row0 + 8 * ty + i;
        float pl = acc[i][0] * ald.x + acc[i][1] * ald.y +
                   acc[i][2] * ald.z + acc[i][3] * ald.w;
        float pr = acc[i][0] * ard.x + acc[i][1] * ard.y +
                   acc[i][2] * ard.z + acc[i][3] * ard.w;
#pragma unroll
        for (int off = 8; off >= 1; off >>= 1) {
            pl += __shfl_xor(pl, off);
            pr += __shfl_xor(pr, off);
        }
        if (row < n) {
            float4 st = make_float4(acc[i][0], acc[i][1], acc[i][2], acc[i][3]);
            *(float4*)(feat + (size_t)row * HF + 4 * tx) = st;
            if (tx == 0) { el[row] = pl; er[row] = pr; }
        }
    }
}

// ======================= fused per-node softmax-aggregate (R10 proven) ====
__global__ __launch_bounds__(256) void node_agg(
    const int* __restrict__ curdeg, const int* __restrict__ esrc,
    const float* __restrict__ el, const float* __restrict__ er,
    const float* __restrict__ feat, const float* __restrict__ bias,
    float* __restrict__ out, int n)
{
    const int node = blockIdx.x * 4 + (threadIdx.x >> 6);
    if (node >= n) return;
    const int lane = threadIdx.x & 63;
    const int cx = lane & 15;
    const int lg = lane >> 4;

    const int cd = curdeg[node];
    const int dg = cd & 511;

    if (dg == 0) {
        if (lane < 16) {
            float4 b4 = *(const float4*)(bias + 4 * cx);
            float4 o;
            o.x = fmaxf(b4.x, 0.f); o.y = fmaxf(b4.y, 0.f);
            o.z = fmaxf(b4.z, 0.f); o.w = fmaxf(b4.w, 0.f);
            *(float4*)(out + (size_t)node * HF + 4 * cx) = o;
        }
        return;
    }

    const int base = ((unsigned)cd >> 9) - dg;
    const float erd = er[node];

    if (dg <= 32) {
        int sreg = 0;
        if (lane < dg) sreg = esrc[base + lane];
        float elv = 0.f;
        if (lane < dg) elv = el[sreg];

        int sj[8];
#pragma unroll
        for (int t = 0; t < 8; ++t) sj[t] = __shfl(sreg, lg + 4 * t);

        float4 f[8];
#pragma unroll
        for (int t = 0; t < 8; ++t)
            if (lg + 4 * t < dg)
                f[t] = *(const float4*)(feat + (size_t)sj[t] * HF + 4 * cx);

        float ereg = -INFINITY;
        if (lane < dg) {
            float e = elv + erd;
            ereg = (e >= 0.f) ? e : 0.2f * e;
        }
        float m = ereg;
#pragma unroll
        for (int off = 32; off >= 1; off >>= 1)
            m = fmaxf(m, __shfl_xor(m, off));
        float ee = __expf(ereg - m);
        float den = ee;
#pragma unroll
        for (int off = 32; off >= 1; off >>= 1)
            den += __shfl_xor(den, off);

        float4 c[4];
#pragma unroll
        for (int q = 0; q < 4; ++q) c[q] = make_float4(0.f, 0.f, 0.f, 0.f);
#pragma unroll
        for (int t = 0; t < 8; ++t) {
            float w = __shfl(ee, lg + 4 * t);
            if (lg + 4 * t < dg) {
                c[t & 3].x += w * f[t].x;
                c[t & 3].y += w * f[t].y;
                c[t & 3].z += w * f[t].z;
                c[t & 3].w += w * f[t].w;
            }
        }
        float4 acc;
        acc.x = (c[0].x + c[1].x) + (c[2].x + c[3].x);
        acc.y = (c[0].y + c[1].y) + (c[2].y + c[3].y);
        acc.z = (c[0].z + c[1].z) + (c[2].z + c[3].z);
        acc.w = (c[0].w + c[1].w) + (c[2].w + c[3].w);
#pragma unroll
        for (int off = 16; off <= 32; off <<= 1) {
            acc.x += __shfl_xor(acc.x, off);
            acc.y += __shfl_xor(acc.y, off);
            acc.z += __shfl_xor(acc.z, off);
            acc.w += __shfl_xor(acc.w, off);
        }
        if (lane < 16) {
            float inv = 1.f / den;
            float4 b4 = *(const float4*)(bias + 4 * cx);
            float4 o;
            o.x = fmaxf(acc.x * inv + b4.x, 0.f);
            o.y = fmaxf(acc.y * inv + b4.y, 0.f);
            o.z = fmaxf(acc.z * inv + b4.z, 0.f);
            o.w = fmaxf(acc.w * inv + b4.w, 0.f);
            *(float4*)(out + (size_t)node * HF + 4 * cx) = o;
        }
        return;
    }

    if (dg <= 64) {
        int sreg = 0;
        float ereg = -INFINITY;
        if (lane < dg) {
            sreg = esrc[base + lane];
            float e = el[sreg] + erd;
            ereg = (e >= 0.f) ? e : 0.2f * e;
        }
        float m = ereg;
#pragma unroll
        for (int off = 32; off >= 1; off >>= 1)
            m = fmaxf(m, __shfl_xor(m, off));
        float ee = __expf(ereg - m);
        float den = ee;
#pragma unroll
        for (int off = 32; off >= 1; off >>= 1)
            den += __shfl_xor(den, off);

        float4 c[4];
#pragma unroll
        for (int q = 0; q < 4; ++q) c[q] = make_float4(0.f, 0.f, 0.f, 0.f);
        for (int j0 = 0; j0 < dg; j0 += 16) {
#pragma unroll
            for (int q = 0; q < 4; ++q) {
                int jj = j0 + lg + 4 * q;
                int   s = __shfl(sreg, jj & 63);
                float w = __shfl(ee, jj & 63);
                if (jj < dg) {
                    float4 fv = *(const float4*)(feat + (size_t)s * HF + 4 * cx);
                    c[q].x += w * fv.x;
                    c[q].y += w * fv.y;
                    c[q].z += w * fv.z;
                    c[q].w += w * fv.w;
                }
            }
        }
        float4 acc;
        acc.x = (c[0].x + c[1].x) + (c[2].x + c[3].x);
        acc.y = (c[0].y + c[1].y) + (c[2].y + c[3].y);
        acc.z = (c[0].z + c[1].z) + (c[2].z + c[3].z);
        acc.w = (c[0].w + c[1].w) + (c[2].w + c[3].w);
#pragma unroll
        for (int off = 16; off <= 32; off <<= 1) {
            acc.x += __shfl_xor(acc.x, off);
            acc.y += __shfl_xor(acc.y, off);
            acc.z += __shfl_xor(acc.z, off);
            acc.w += __shfl_xor(acc.w, off);
        }
        if (lane < 16) {
            float inv = 1.f / den;
            float4 b4 = *(const float4*)(bias + 4 * cx);
            float4 o;
            o.x = fmaxf(acc.x * inv + b4.x, 0.f);
            o.y = fmaxf(acc.y * inv + b4.y, 0.f);
            o.z = fmaxf(acc.z * inv + b4.z, 0.f);
            o.w = fmaxf(acc.w * inv + b4.w, 0.f);
            *(float4*)(out + (size_t)node * HF + 4 * cx) = o;
        }
        return;
    }

    // slow path (deg > 64)
    float m = -INFINITY;
    for (int j = lane; j < dg; j += 64) {
        int s = esrc[base + j];
        float e = el[s] + erd;
        e = (e >= 0.f) ? e : 0.2f * e;
        m = fmaxf(m, e);
    }
#pragma unroll
    for (int off = 32; off >= 1; off >>= 1)
        m = fmaxf(m, __shfl_xor(m, off));

    float acc = 0.f, den = 0.f;
    for (int j = 0; j < dg; ++j) {
        int s = esrc[base + j];
        float e = el[s] + erd;
        e = (e >= 0.f) ? e : 0.2f * e;
        float ee = __expf(e - m);
        den += ee;
        acc += ee * feat[(size_t)s * HF + lane];
    }
    out[(size_t)node * HF + lane] = fmaxf(acc / den + bias[lane], 0.f);
}

extern "C" void kernel_launch(void* const* d_in, const int* in_sizes, int n_in,
                              void* d_out, int out_size, void* d_ws, size_t ws_size,
                              hipStream_t stream) {
    const int N = NNODES;
    const int E = NEDGES;

    const float* in_feat = (const float*)d_in[0];
    const float* W1 = (const float*)d_in[1];
    const float* al1 = (const float*)d_in[2];
    const float* ar1 = (const float*)d_in[3];
    const float* b1 = (const float*)d_in[4];
    const float* W2 = (const float*)d_in[5];
    const float* al2 = (const float*)d_in[6];
    const float* ar2 = (const float*)d_in[7];
    const float* b2 = (const float*)d_in[8];
    const float* W3 = (const float*)d_in[9];
    const float* al3 = (const float*)d_in[10];
    const float* ar3 = (const float*)d_in[11];
    const float* b3 = (const float*)d_in[12];
    const int* src = (const int*)d_in[13];
    const int* dst = (const int*)d_in[14];

    float* ws = (float*)d_ws;
    float* feat = ws;                          // N*64
    float* h1   = feat + (size_t)N * HF;       // N*64 (aliased by epack pre-layer1)
    float* h2   = h1 + (size_t)N * HF;         // N*64
    float* el   = h2 + (size_t)N * HF;         // N
    float* er   = el + N;                      // N
    int* curdeg = (int*)(er + N);              // N
    int* gcur   = curdeg + N;                  // 256
    int* esrc   = gcur + 256;                  // NBUCK_USED*BCAP = 1.807M
    int* epack  = (int*)h1;                    // NBUCK_USED*BCAP ints (7.2MB of h1)

    const int gNode4 = (N + 3) / 4;
    const int gTile = (N + 127) / 128;

    // ---- CSR build (fixed-capacity buckets; same graph for all 3 layers) ----
    k_ginit<<<1, 256, 0, stream>>>(gcur);
    k_bucket<<<KB_BLOCKS, 256, 0, stream>>>(src, dst, gcur, epack, E);
    k_local<<<NBUCK_USED, 256, 0, stream>>>(epack, gcur, curdeg, esrc);

    float* out = (float*)d_out;

    // ---- layer 1 (K=128) ----
    gemm_tile<128><<<gTile, 256, 0, stream>>>(in_feat, W1, al1, ar1, feat, el, er, N);
    node_agg<<<gNode4, 256, 0, stream>>>(curdeg, esrc, el, er, feat, b1, h1, N);

    // ---- layer 2 (K=64) ----
    gemm_tile<64><<<gTile, 256, 0, stream>>>(h1, W2, al2, ar2, feat, el, er, N);
    node_agg<<<gNode4, 256, 0, stream>>>(curdeg, esrc, el, er, feat, b2, h2, N);

    // ---- layer 3 (K=64) ----
    gemm_tile<64><<<gTile, 256, 0, stream>>>(h2, W3, al3, ar3, feat, el, er, N);
    node_agg<<<gNode4, 256, 0, stream>>>(curdeg, esrc, el, er, feat, b3, out, N);
}

// Round 16
// 316.630 us; speedup vs baseline: 1.0123x; 1.0123x over previous
//
#include <hip/hip_runtime.h>
#include <math.h>

#define NNODES 100000
#define NEDGES 1600000
#define HF 64
#define NBUCK_SHIFT 9
#define NBUCK 256                                // counter slots (power of 2)
#define NBUCK_USED ((NNODES + 511) >> 9)         // 196 buckets actually used
#define BCAP 9216                                // per-bucket capacity (mean 8192 + 11 sigma)
#define KB_BLOCKS 1024

// ======================= CSR build (fixed-capacity buckets) ===============
__global__ __launch_bounds__(256) void k_ginit(int* __restrict__ gcur)
{
    gcur[threadIdx.x] = threadIdx.x * BCAP;
}

// pass 1: partition edges into dst-buckets; payload packed (src<<9)|localdst
__global__ __launch_bounds__(256) void k_bucket(
    const int* __restrict__ src, const int* __restrict__ dst,
    int* __restrict__ gcur, int* __restrict__ epack, int E)
{
    __shared__ int hist[NBUCK];
    const int tid = threadIdx.x;
    const int EPB = (E + KB_BLOCKS - 1) / KB_BLOCKS;
    const int e0 = blockIdx.x * EPB;
    const int e1 = min(E, e0 + EPB);

    hist[tid] = 0;
    __syncthreads();
    for (int i = e0 + tid; i < e1; i += 256)
        atomicAdd(&hist[dst[i] >> NBUCK_SHIFT], 1);
    __syncthreads();
    int cnt = hist[tid];
    int base = (cnt > 0) ? atomicAdd(&gcur[tid], cnt) : 0;
    __syncthreads();
    hist[tid] = base;
    __syncthreads();
    for (int i = e0 + tid; i < e1; i += 256) {
        int d = dst[i];
        int r = atomicAdd(&hist[d >> NBUCK_SHIFT], 1);
        epack[r] = (src[i] << NBUCK_SHIFT) | (d & 511);
    }
}

// pass 2: per-bucket local CSR — LDS histogram + scan + scatter.
__global__ __launch_bounds__(256) void k_local(
    const int* __restrict__ epack, const int* __restrict__ gcur,
    int* __restrict__ curdeg, int* __restrict__ esrc)
{
    __shared__ int lhist[512];
    __shared__ int lcur[512];
    __shared__ int s[256];
    const int b = blockIdx.x;
    const int tid = threadIdx.x;
    const int e0 = b * BCAP;
    const int e1 = gcur[b];
    const int n0 = b << NBUCK_SHIFT;

    lhist[tid] = 0;
    lhist[tid + 256] = 0;
    __syncthreads();
    for (int i = e0 + tid; i < e1; i += 256)
        atomicAdd(&lhist[epack[i] & 511], 1);
    __syncthreads();

    int v0 = lhist[2 * tid], v1 = lhist[2 * tid + 1];
    int tsum = v0 + v1;
    s[tid] = tsum;
    __syncthreads();
    for (int off = 1; off < 256; off <<= 1) {
        int t = (tid >= off) ? s[tid - off] : 0;
        __syncthreads();
        s[tid] += t;
        __syncthreads();
    }
    int run = s[tid] - tsum;
    lcur[2 * tid] = run;
    lcur[2 * tid + 1] = run + v0;
    int node0 = n0 + 2 * tid;
    if (node0 < NNODES)     curdeg[node0]     = ((e0 + run + v0) << 9) | v0;
    if (node0 + 1 < NNODES) curdeg[node0 + 1] = ((e0 + run + v0 + v1) << 9) | v1;
    __syncthreads();

    for (int i = e0 + tid; i < e1; i += 256) {
        int p = epack[i];
        int pos = atomicAdd(&lcur[p & 511], 1);
        esrc[e0 + pos] = ((unsigned)p) >> NBUCK_SHIFT;
    }
}

// ======================= tiled GEMM (R13-proven: 128x64, 8x4, KS=32) ======
template <int K>
__global__ __launch_bounds__(256) void gemm_tile(
    const float* __restrict__ x, const float* __restrict__ W,
    const float* __restrict__ al, const float* __restrict__ ar,
    float* __restrict__ feat, float* __restrict__ el, float* __restrict__ er,
    int n)
{
    constexpr int KS = 32;
    __shared__ float xs[KS][132];
    __shared__ float wt[KS][68];

    const int tid = threadIdx.x;
    const int tx = tid & 15;
    const int ty = tid >> 4;
    const int row0 = blockIdx.x * 128;

    float acc[8][4];
#pragma unroll
    for (int i = 0; i < 8; ++i)
#pragma unroll
        for (int j = 0; j < 4; ++j) acc[i][j] = 0.f;

    for (int ks = 0; ks < K; ks += KS) {
        if (ks) __syncthreads();
#pragma unroll
        for (int jj = 0; jj < 4; ++jj) {
            int j = tid + jj * 256;
            int r = j >> 3;
            int k4 = j & 7;
            int gr = row0 + r;
            float4 v = make_float4(0.f, 0.f, 0.f, 0.f);
            if (gr < n) v = *(const float4*)(x + (size_t)gr * K + ks + 4 * k4);
            xs[4 * k4 + 0][r] = v.x;
            xs[4 * k4 + 1][r] = v.y;
            xs[4 * k4 + 2][r] = v.z;
            xs[4 * k4 + 3][r] = v.w;
        }
#pragma unroll
        for (int jj = 0; jj < 2; ++jj) {
            int j = tid + jj * 256;
            int c = j >> 3;
            int k4 = j & 7;
            float4 v = *(const float4*)(W + (size_t)c * K + ks + 4 * k4);
            wt[4 * k4 + 0][c] = v.x;
            wt[4 * k4 + 1][c] = v.y;
            wt[4 * k4 + 2][c] = v.z;
            wt[4 * k4 + 3][c] = v.w;
        }
        __syncthreads();

#pragma unroll 8
        for (int k = 0; k < KS; ++k) {
            float4 a0 = *(const float4*)&xs[k][8 * ty + 0];
            float4 a1 = *(const float4*)&xs[k][8 * ty + 4];
            float4 b  = *(const float4*)&wt[k][4 * tx];
            float av[8] = {a0.x, a0.y, a0.z, a0.w, a1.x, a1.y, a1.z, a1.w};
            float bv[4] = {b.x, b.y, b.z, b.w};
#pragma unroll
            for (int i = 0; i < 8; ++i)
#pragma unroll
                for (int j = 0; j < 4; ++j)
                    acc[i][j] += av[i] * bv[j];
        }
    }

    const float4 ald = *(const float4*)(al + 4 * tx);
    const float4 ard = *(const float4*)(ar + 4 * tx);
#pragma unroll
    for (int i = 0; i < 8; ++i) {
        int row = row0 + 8 * ty + i;
        float pl = acc[i][0] * ald.x + acc[i][1] * ald.y +
                   acc[i][2] * ald.z + acc[i][3] * ald.w;
        float pr = acc[i][0] * ard.x + acc[i][1] * ard.y +
                   acc[i][2] * ard.z + acc[i][3] * ard.w;
#pragma unroll
        for (int off = 8; off >= 1; off >>= 1) {
            pl += __shfl_xor(pl, off);
            pr += __shfl_xor(pr, off);
        }
        if (row < n) {
            float4 st = make_float4(acc[i][0], acc[i][1], acc[i][2], acc[i][3]);
            *(float4*)(feat + (size_t)row * HF + 4 * tx) = st;
            if (tx == 0) { el[row] = pl; er[row] = pr; }
        }
    }
}

// ======================= fused per-node softmax-aggregate (R10 proven) ====
__global__ __launch_bounds__(256) void node_agg(
    const int* __restrict__ curdeg, const int* __restrict__ esrc,
    const float* __restrict__ el, const float* __restrict__ er,
    const float* __restrict__ feat, const float* __restrict__ bias,
    float* __restrict__ out, int n)
{
    const int node = blockIdx.x * 4 + (threadIdx.x >> 6);
    if (node >= n) return;
    const int lane = threadIdx.x & 63;
    const int cx = lane & 15;
    const int lg = lane >> 4;

    const int cd = curdeg[node];
    const int dg = cd & 511;

    if (dg == 0) {
        if (lane < 16) {
            float4 b4 = *(const float4*)(bias + 4 * cx);
            float4 o;
            o.x = fmaxf(b4.x, 0.f); o.y = fmaxf(b4.y, 0.f);
            o.z = fmaxf(b4.z, 0.f); o.w = fmaxf(b4.w, 0.f);
            *(float4*)(out + (size_t)node * HF + 4 * cx) = o;
        }
        return;
    }

    const int base = ((unsigned)cd >> 9) - dg;
    const float erd = er[node];

    if (dg <= 32) {
        int sreg = 0;
        if (lane < dg) sreg = esrc[base + lane];
        float elv = 0.f;
        if (lane < dg) elv = el[sreg];

        int sj[8];
#pragma unroll
        for (int t = 0; t < 8; ++t) sj[t] = __shfl(sreg, lg + 4 * t);

        float4 f[8];
#pragma unroll
        for (int t = 0; t < 8; ++t)
            if (lg + 4 * t < dg)
                f[t] = *(const float4*)(feat + (size_t)sj[t] * HF + 4 * cx);

        float ereg = -INFINITY;
        if (lane < dg) {
            float e = elv + erd;
            ereg = (e >= 0.f) ? e : 0.2f * e;
        }
        float m = ereg;
#pragma unroll
        for (int off = 32; off >= 1; off >>= 1)
            m = fmaxf(m, __shfl_xor(m, off));
        float ee = __expf(ereg - m);
        float den = ee;
#pragma unroll
        for (int off = 32; off >= 1; off >>= 1)
            den += __shfl_xor(den, off);

        float4 c[4];
#pragma unroll
        for (int q = 0; q < 4; ++q) c[q] = make_float4(0.f, 0.f, 0.f, 0.f);
#pragma unroll
        for (int t = 0; t < 8; ++t) {
            float w = __shfl(ee, lg + 4 * t);
            if (lg + 4 * t < dg) {
                c[t & 3].x += w * f[t].x;
                c[t & 3].y += w * f[t].y;
                c[t & 3].z += w * f[t].z;
                c[t & 3].w += w * f[t].w;
            }
        }
        float4 acc;
        acc.x = (c[0].x + c[1].x) + (c[2].x + c[3].x);
        acc.y = (c[0].y + c[1].y) + (c[2].y + c[3].y);
        acc.z = (c[0].z + c[1].z) + (c[2].z + c[3].z);
        acc.w = (c[0].w + c[1].w) + (c[2].w + c[3].w);
#pragma unroll
        for (int off = 16; off <= 32; off <<= 1) {
            acc.x += __shfl_xor(acc.x, off);
            acc.y += __shfl_xor(acc.y, off);
            acc.z += __shfl_xor(acc.z, off);
            acc.w += __shfl_xor(acc.w, off);
        }
        if (lane < 16) {
            float inv = 1.f / den;
            float4 b4 = *(const float4*)(bias + 4 * cx);
            float4 o;
            o.x = fmaxf(acc.x * inv + b4.x, 0.f);
            o.y = fmaxf(acc.y * inv + b4.y, 0.f);
            o.z = fmaxf(acc.z * inv + b4.z, 0.f);
            o.w = fmaxf(acc.w * inv + b4.w, 0.f);
            *(float4*)(out + (size_t)node * HF + 4 * cx) = o;
        }
        return;
    }

    if (dg <= 64) {
        int sreg = 0;
        float ereg = -INFINITY;
        if (lane < dg) {
            sreg = esrc[base + lane];
            float e = el[sreg] + erd;
            ereg = (e >= 0.f) ? e : 0.2f * e;
        }
        float m = ereg;
#pragma unroll
        for (int off = 32; off >= 1; off >>= 1)
            m = fmaxf(m, __shfl_xor(m, off));
        float ee = __expf(ereg - m);
        float den = ee;
#pragma unroll
        for (int off = 32; off >= 1; off >>= 1)
            den += __shfl_xor(den, off);

        float4 c[4];
#pragma unroll
        for (int q = 0; q < 4; ++q) c[q] = make_float4(0.f, 0.f, 0.f, 0.f);
        for (int j0 = 0; j0 < dg; j0 += 16) {
#pragma unroll
            for (int q = 0; q < 4; ++q) {
                int jj = j0 + lg + 4 * q;
                int   s = __shfl(sreg, jj & 63);
                float w = __shfl(ee, jj & 63);
                if (jj < dg) {
                    float4 fv = *(const float4*)(feat + (size_t)s * HF + 4 * cx);
                    c[q].x += w * fv.x;
                    c[q].y += w * fv.y;
                    c[q].z += w * fv.z;
                    c[q].w += w * fv.w;
                }
            }
        }
        float4 acc;
        acc.x = (c[0].x + c[1].x) + (c[2].x + c[3].x);
        acc.y = (c[0].y + c[1].y) + (c[2].y + c[3].y);
        acc.z = (c[0].z + c[1].z) + (c[2].z + c[3].z);
        acc.w = (c[0].w + c[1].w) + (c[2].w + c[3].w);
#pragma unroll
        for (int off = 16; off <= 32; off <<= 1) {
            acc.x += __shfl_xor(acc.x, off);
            acc.y += __shfl_xor(acc.y, off);
            acc.z += __shfl_xor(acc.z, off);
            acc.w += __shfl_xor(acc.w, off);
        }
        if (lane < 16) {
            float inv = 1.f / den;
            float4 b4 = *(const float4*)(bias + 4 * cx);
            float4 o;
            o.x = fmaxf(acc.x * inv + b4.x, 0.f);
            o.y = fmaxf(acc.y * inv + b4.y, 0.f);
            o.z = fmaxf(acc.z * inv + b4.z, 0.f);
            o.w = fmaxf(acc.w * inv + b4.w, 0.f);
            *(float4*)(out + (size_t)node * HF + 4 * cx) = o;
        }
        return;
    }

    // slow path (deg > 64)
    float m = -INFINITY;
    for (int j = lane; j < dg; j += 64) {
        int s = esrc[base + j];
        float e = el[s] + erd;
        e = (e >= 0.f) ? e : 0.2f * e;
        m = fmaxf(m, e);
    }
#pragma unroll
    for (int off = 32; off >= 1; off >>= 1)
        m = fmaxf(m, __shfl_xor(m, off));

    float acc = 0.f, den = 0.f;
    for (int j = 0; j < dg; ++j) {
        int s = esrc[base + j];
        float e = el[s] + erd;
        e = (e >= 0.f) ? e : 0.2f * e;
        float ee = __expf(e - m);
        den += ee;
        acc += ee * feat[(size_t)s * HF + lane];
    }
    out[(size_t)node * HF + lane] = fmaxf(acc / den + bias[lane], 0.f);
}

extern "C" void kernel_launch(void* const* d_in, const int* in_sizes, int n_in,
                              void* d_out, int out_size, void* d_ws, size_t ws_size,
                              hipStream_t stream) {
    const int N = NNODES;
    const int E = NEDGES;

    const float* in_feat = (const float*)d_in[0];
    const float* W1 = (const float*)d_in[1];
    const float* al1 = (const float*)d_in[2];
    const float* ar1 = (const float*)d_in[3];
    const float* b1 = (const float*)d_in[4];
    const float* W2 = (const float*)d_in[5];
    const float* al2 = (const float*)d_in[6];
    const float* ar2 = (const float*)d_in[7];
    const float* b2 = (const float*)d_in[8];
    const float* W3 = (const float*)d_in[9];
    const float* al3 = (const float*)d_in[10];
    const float* ar3 = (const float*)d_in[11];
    const float* b3 = (const float*)d_in[12];
    const int* src = (const int*)d_in[13];
    const int* dst = (const int*)d_in[14];

    float* ws = (float*)d_ws;
    float* feat = ws;                          // N*64
    float* h1   = feat + (size_t)N * HF;       // N*64 (aliased by epack pre-layer1)
    float* h2   = h1 + (size_t)N * HF;         // N*64
    float* el   = h2 + (size_t)N * HF;         // N
    float* er   = el + N;                      // N
    int* curdeg = (int*)(er + N);              // N
    int* gcur   = curdeg + N;                  // 256
    int* esrc   = gcur + 256;                  // NBUCK_USED*BCAP = 1.807M
    int* epack  = (int*)h1;                    // NBUCK_USED*BCAP ints (7.2MB of h1)

    const int gNode4 = (N + 3) / 4;
    const int gTile = (N + 127) / 128;

    // ---- CSR build (fixed-capacity buckets; same graph for all 3 layers) ----
    k_ginit<<<1, 256, 0, stream>>>(gcur);
    k_bucket<<<KB_BLOCKS, 256, 0, stream>>>(src, dst, gcur, epack, E);
    k_local<<<NBUCK_USED, 256, 0, stream>>>(epack, gcur, curdeg, esrc);

    float* out = (float*)d_out;

    // ---- layer 1 (K=128) ----
    gemm_tile<128><<<gTile, 256, 0, stream>>>(in_feat, W1, al1, ar1, feat, el, er, N);
    node_agg<<<gNode4, 256, 0, stream>>>(curdeg, esrc, el, er, feat, b1, h1, N);

    // ---- layer 2 (K=64) ----
    gemm_tile<64><<<gTile, 256, 0, stream>>>(h1, W2, al2, ar2, feat, el, er, N);
    node_agg<<<gNode4, 256, 0, stream>>>(curdeg, esrc, el, er, feat, b2, h2, N);

    // ---- layer 3 (K=64) ----
    gemm_tile<64><<<gTile, 256, 0, stream>>>(h2, W3, al3, ar3, feat, el, er, N);
    node_agg<<<gNode4, 256, 0, stream>>>(curdeg, esrc, el, er, feat, b3, out, N);
}